// Round 2
// baseline (1801.020 us; speedup 1.0000x reference)
//
#include <hip/hip_runtime.h>
#include <stdint.h>

#define N_T 32768
#define N_Q 4096
#define E_T 1048576
#define E_Q 131072
#define H   128
#define NL  3

typedef float  f32x4  __attribute__((ext_vector_type(4)));
typedef short  s16x8  __attribute__((ext_vector_type(8)));

// ---------------- utility kernels ----------------
__global__ void zero_i32_k(int* p, int n){
  int i = blockIdx.x*blockDim.x + threadIdx.x;
  if(i<n) p[i]=0;
}
__global__ void zero_f32_k(float* p, int n){
  int i = blockIdx.x*blockDim.x + threadIdx.x;
  if(i<n) p[i]=0.f;
}

// classify mask dtype: flag bit0 -> uint8 bools, bit1 -> float32, 0 -> int32
__global__ void detect_mask_k(const unsigned* m, int* flag){
  int t = threadIdx.x;
  int f = 0;
  for(int j=t;j<4096;j+=256){
    unsigned v = m[j];
    if(v > 1u) f |= (v & 0xFEFEFEFEu) ? 2 : 1;
  }
  if(f) atomicOr(flag, f);
}

// ---------------- CSR build ----------------
__global__ void count_k(const int* __restrict__ dst, int E, int* cnt){
  int i = blockIdx.x*blockDim.x + threadIdx.x;
  if(i<E) atomicAdd(&cnt[dst[i]], 1);
}

__global__ void scan_k(const int* __restrict__ cnt, int n, int* rp, int* pos){
  __shared__ int part[1024];
  int t = threadIdx.x;
  int chunk = (n + 1023) >> 10;
  int lo = t*chunk, hi = lo+chunk; if(hi>n) hi=n;
  int s = 0;
  for(int i=lo;i<hi;i++) s += cnt[i];
  part[t] = s;
  __syncthreads();
  for(int off=1; off<1024; off<<=1){
    int v = (t >= off) ? part[t-off] : 0;
    __syncthreads();
    part[t] += v;
    __syncthreads();
  }
  int run = (t==0) ? 0 : part[t-1];
  for(int i=lo;i<hi;i++){ rp[i]=run; pos[i]=run; run += cnt[i]; }
  if(t==0) rp[n] = part[1023];
}

__global__ void fill_k(const int* __restrict__ src, const int* __restrict__ dst,
                       int E, int* pos, int* csr){
  int i = blockIdx.x*blockDim.x + threadIdx.x;
  if(i<E){
    int p = atomicAdd(&pos[dst[i]], 1);
    csr[p] = src[i];
  }
}

// ---------------- embedding gather ----------------
__global__ void embed_k(const int* __restrict__ idx, const float* __restrict__ emb,
                        float* __restrict__ out, int N){
  int i = blockIdx.x*blockDim.x + threadIdx.x;   // N*32 threads
  int n = i >> 5, c = i & 31;
  if(n < N){
    ((float4*)out)[(size_t)n*32 + c] = ((const float4*)emb)[(size_t)idx[n]*32 + c];
  }
}

// ---------------- segment mean (one wave per dst node) ----------------
__global__ void agg_k(const float* __restrict__ x, const int* __restrict__ rp,
                      const int* __restrict__ csr, float* __restrict__ agg, int N){
  int wid = (int)(((size_t)blockIdx.x*blockDim.x + threadIdx.x) >> 6);
  int lane = threadIdx.x & 63;
  if(wid >= N) return;
  int rs = rp[wid], re = rp[wid+1];
  float ax=0.f, ay=0.f;
  for(int j=rs;j<re;j++){
    int s = csr[j];
    float2 v = ((const float2*)x)[(size_t)s*64 + lane];
    ax += v.x; ay += v.y;
  }
  int c = re - rs; if(c < 1) c = 1;
  float inv = 1.0f / (float)c;
  float2 o; o.x = ax*inv; o.y = ay*inv;
  ((float2*)agg)[(size_t)wid*64 + lane] = o;
}

// bf16 hi/lo split (round-to-nearest-even-ish with simple RN)
__device__ inline void bf16_split(float x, ushort& hi, ushort& lo){
  union { float f; unsigned u; } v; v.f = x;
  unsigned r = (v.u + 0x7FFFu + ((v.u >> 16) & 1u)) & 0xFFFF0000u;
  hi = (ushort)(r >> 16);
  union { unsigned u; float f; } h; h.u = r;
  float rem = x - h.f;
  union { float f; unsigned u; } w; w.f = rem;
  unsigned r2 = (w.u + 0x7FFFu + ((w.u >> 16) & 1u)) & 0xFFFF0000u;
  lo = (ushort)(r2 >> 16);
}

// ---------------- layer GEMM: out = elu(agg@Wl.T + bl + x@Wr.T) ----------------
// 128x128 tile, 256 threads, 8x8 per thread, two K=128 phases
__global__ __launch_bounds__(256,1) void layer_k(
    const float* __restrict__ agg, const float* __restrict__ x,
    const float* __restrict__ Wl, const float* __restrict__ Wr,
    const float* __restrict__ bl, float* __restrict__ outf,
    ushort* __restrict__ outHi, ushort* __restrict__ outLo,
    int N, int last){
  __shared__ float WT[128*128];
  __shared__ float AT[128*128];
  int t = threadIdx.x;
  int r0g = blockIdx.x * 128;
  int rg = t & 15, cg = t >> 4;
  int r0 = rg*8, c0 = cg*8;
  float acc[8][8] = {};
  for(int ph=0; ph<2; ph++){
    const float* W = ph ? Wr : Wl;
    const float* A = ph ? x : agg;
    if(ph) __syncthreads();
    #pragma unroll
    for(int i=0;i<16;i++){
      int lin = t + i*256;            // 0..4095
      int c = lin & 127, kg = lin >> 7;
      float4 w = *(const float4*)&W[(size_t)c*H + kg*4];
      WT[(kg*4+0)*128 + c] = w.x;
      WT[(kg*4+1)*128 + c] = w.y;
      WT[(kg*4+2)*128 + c] = w.z;
      WT[(kg*4+3)*128 + c] = w.w;
      float4 a = *(const float4*)&A[(size_t)(r0g + c)*H + kg*4];
      AT[(kg*4+0)*128 + c] = a.x;
      AT[(kg*4+1)*128 + c] = a.y;
      AT[(kg*4+2)*128 + c] = a.z;
      AT[(kg*4+3)*128 + c] = a.w;
    }
    __syncthreads();
    for(int k=0;k<128;k++){
      float4 a0 = *(float4*)&AT[k*128 + r0];
      float4 a1 = *(float4*)&AT[k*128 + r0+4];
      float4 w0 = *(float4*)&WT[k*128 + c0];
      float4 w1 = *(float4*)&WT[k*128 + c0+4];
      float av[8] = {a0.x,a0.y,a0.z,a0.w,a1.x,a1.y,a1.z,a1.w};
      float wv[8] = {w0.x,w0.y,w0.z,w0.w,w1.x,w1.y,w1.z,w1.w};
      #pragma unroll
      for(int rr=0;rr<8;rr++)
        #pragma unroll
        for(int cc=0;cc<8;cc++)
          acc[rr][cc] += av[rr]*wv[cc];
    }
  }
  #pragma unroll
  for(int rr=0;rr<8;rr++)
    #pragma unroll
    for(int cc=0;cc<8;cc++){
      float v = acc[rr][cc] + bl[c0+cc];
      acc[rr][cc] = (v > 0.f) ? v : expm1f(v);
    }
  if(!last){
    #pragma unroll
    for(int rr=0;rr<8;rr++){
      float4 v0; v0.x=acc[rr][0]; v0.y=acc[rr][1]; v0.z=acc[rr][2]; v0.w=acc[rr][3];
      float4 v1; v1.x=acc[rr][4]; v1.y=acc[rr][5]; v1.z=acc[rr][6]; v1.w=acc[rr][7];
      size_t off = (size_t)(r0g + r0 + rr)*H + c0;
      *(float4*)&outf[off]   = v0;
      *(float4*)&outf[off+4] = v1;
    }
  } else {
    #pragma unroll
    for(int rr=0;rr<8;rr++){
      ushort hh[8], ll[8];
      #pragma unroll
      for(int cc=0;cc<8;cc++) bf16_split(acc[rr][cc], hh[cc], ll[cc]);
      uint4 hv, lv;
      hv.x = (unsigned)hh[0] | ((unsigned)hh[1]<<16);
      hv.y = (unsigned)hh[2] | ((unsigned)hh[3]<<16);
      hv.z = (unsigned)hh[4] | ((unsigned)hh[5]<<16);
      hv.w = (unsigned)hh[6] | ((unsigned)hh[7]<<16);
      lv.x = (unsigned)ll[0] | ((unsigned)ll[1]<<16);
      lv.y = (unsigned)ll[2] | ((unsigned)ll[3]<<16);
      lv.z = (unsigned)ll[4] | ((unsigned)ll[5]<<16);
      lv.w = (unsigned)ll[6] | ((unsigned)ll[7]<<16);
      size_t off = (size_t)(r0g + r0 + rr)*H + c0;
      *(uint4*)&outHi[off] = hv;
      *(uint4*)&outLo[off] = lv;
    }
  }
}

// ---------------- attention pass 1: MFMA bf16 split GEMM + exp + rowsum ----------------
// 128x128 out tile, 256 threads = 4 waves (2x2), 64x64 per wave, K staged in two 64-halves
__global__ __launch_bounds__(256,2) void att1_k(
    const ushort* __restrict__ eqHi, const ushort* __restrict__ eqLo,
    const ushort* __restrict__ etHi, const ushort* __restrict__ etLo,
    const void* __restrict__ maskp, const int* __restrict__ flag,
    float* __restrict__ out, float* __restrict__ rowsum){
  __shared__ ushort SM[4*128*64];   // QH | QL | TH | TL, each [128][64] swizzled
  ushort* QH = SM;
  ushort* QL = SM + 8192;
  ushort* TH = SM + 16384;
  ushort* TL = SM + 24576;

  int t = threadIdx.x;
  int gc0 = blockIdx.x * 128;   // target cols
  int gr0 = blockIdx.y * 128;   // query rows
  int lane = t & 63;
  int w = t >> 6;
  int wr = w >> 1, wc = w & 1;
  int fr = lane & 15, kg0 = lane >> 4;

  f32x4 acc[4][4] = {};

  for(int kt=0; kt<2; kt++){
    if(kt) __syncthreads();
    // stage 4 tiles: each [128 rows][64 k] bf16, slot-swizzled (slot ^= row&7)
    #pragma unroll
    for(int it=0; it<4; it++){
      int idx = t + it*256;          // 0..1023
      int row = idx >> 3, k8 = idx & 7;
      int sw = (k8 ^ (row & 7)) * 8;
      size_t goffQ = (size_t)(gr0 + row)*H + kt*64 + k8*8;
      size_t goffT = (size_t)(gc0 + row)*H + kt*64 + k8*8;
      *(uint4*)&QH[row*64 + sw] = *(const uint4*)&eqHi[goffQ];
      *(uint4*)&QL[row*64 + sw] = *(const uint4*)&eqLo[goffQ];
      *(uint4*)&TH[row*64 + sw] = *(const uint4*)&etHi[goffT];
      *(uint4*)&TL[row*64 + sw] = *(const uint4*)&etLo[goffT];
    }
    __syncthreads();
    #pragma unroll
    for(int s=0; s<2; s++){
      int kg = s*4 + kg0;
      s16x8 ah[4], al[4], bh[4], bl_[4];
      #pragma unroll
      for(int m=0;m<4;m++){
        int ar = wr*64 + m*16 + fr;
        int ia = ar*64 + ((kg ^ (ar & 7)) << 3);
        ah[m] = *(const s16x8*)&QH[ia];
        al[m] = *(const s16x8*)&QL[ia];
      }
      #pragma unroll
      for(int n=0;n<4;n++){
        int bc = wc*64 + n*16 + fr;
        int ib = bc*64 + ((kg ^ (bc & 7)) << 3);
        bh[n] = *(const s16x8*)&TH[ib];
        bl_[n] = *(const s16x8*)&TL[ib];
      }
      #pragma unroll
      for(int m=0;m<4;m++)
        #pragma unroll
        for(int n=0;n<4;n++){
          acc[m][n] = __builtin_amdgcn_mfma_f32_16x16x32_bf16(ah[m], bh[n],  acc[m][n], 0,0,0);
          acc[m][n] = __builtin_amdgcn_mfma_f32_16x16x32_bf16(ah[m], bl_[n], acc[m][n], 0,0,0);
          acc[m][n] = __builtin_amdgcn_mfma_f32_16x16x32_bf16(al[m], bh[n],  acc[m][n], 0,0,0);
        }
    }
  }

  // epilogue: scale, mask, exp, store, row sums
  const float sc = 0.08838834764831845f;   // 1/sqrt(128)
  int mb = *flag;
  const float*   mf = (const float*)maskp;
  const uint8_t* mu = (const uint8_t*)maskp;
  const int*     mi = (const int*)maskp;

  #pragma unroll
  for(int m=0;m<4;m++){
    float rs[4] = {0.f,0.f,0.f,0.f};
    #pragma unroll
    for(int reg=0;reg<4;reg++){
      int row = gr0 + wr*64 + m*16 + kg0*4 + reg;
      size_t rbase = (size_t)row * N_T;
      #pragma unroll
      for(int n=0;n<4;n++){
        int col = gc0 + wc*64 + n*16 + fr;
        size_t off = rbase + col;
        float logit = acc[m][n][reg] * sc;
        bool keep;
        if(mb & 2)      keep = (mf[off] != 0.f);
        else if(mb & 1) keep = (mu[off] != 0);
        else            keep = (mi[off] != 0);
        float p = keep ? __expf(logit) : 0.f;
        out[off] = p;
        rs[reg] += p;
      }
    }
    // reduce across the 16 col-lanes (low 4 bits of lane id)
    #pragma unroll
    for(int reg=0;reg<4;reg++){
      float v = rs[reg];
      v += __shfl_xor(v, 1);
      v += __shfl_xor(v, 2);
      v += __shfl_xor(v, 4);
      v += __shfl_xor(v, 8);
      if(fr == 0){
        int row = gr0 + wr*64 + m*16 + kg0*4 + reg;
        atomicAdd(&rowsum[row], v);
      }
    }
  }
}

// ---------------- attention pass 2: normalize ----------------
__global__ void att2_k(float* __restrict__ out, const float* __restrict__ rowsum){
  size_t n4 = ((size_t)N_Q * N_T) / 4;
  size_t i = (size_t)blockIdx.x*blockDim.x + threadIdx.x;
  size_t stride = (size_t)gridDim.x*blockDim.x;
  for(; i<n4; i+=stride){
    int r = (int)(i >> 13);          // (i*4)/32768
    float inv = 1.0f / rowsum[r];
    float4 v = ((float4*)out)[i];
    v.x*=inv; v.y*=inv; v.z*=inv; v.w*=inv;
    ((float4*)out)[i] = v;
  }
}

// ---------------- host launch ----------------
extern "C" void kernel_launch(void* const* d_in, const int* in_sizes, int n_in,
                              void* d_out, int out_size, void* d_ws, size_t ws_size,
                              hipStream_t stream){
  const int* tx  = (const int*)d_in[0];
  const int* qx  = (const int*)d_in[1];
  const int* te  = (const int*)d_in[2];
  const int* qe  = (const int*)d_in[3];
  const void* mask = d_in[4];
  const float* emb = (const float*)d_in[5];
  const float* Wl  = (const float*)d_in[6];
  const float* bl  = (const float*)d_in[7];
  const float* Wr  = (const float*)d_in[8];
  float* out = (float*)d_out;

  // ws: final features as bf16 hi/lo + rowsum + flag (~19 MB)
  ushort* etHi = (ushort*)d_ws;                       // N_T*H
  ushort* etLo = etHi + (size_t)N_T*H;
  ushort* eqHi = etLo + (size_t)N_T*H;                // N_Q*H
  ushort* eqLo = eqHi + (size_t)N_Q*H;
  float* rowsum = (float*)(eqLo + (size_t)N_Q*H);
  int*   flag   = (int*)(rowsum + N_Q);

  // phase-1 scratch lives inside d_out (512MB; overwritten by att1 afterwards)
  float* S    = out;
  float* xt0  = S;
  float* xt1  = S + 4194304;
  float* aggt = S + 8388608;
  float* xq0  = S + 12582912;
  float* xq1  = xq0 + 524288;
  float* aggq = xq1 + 524288;
  int*   ib    = (int*)(aggq + 524288);
  int*   cnt_t = ib;
  int*   rp_t  = cnt_t + N_T;
  int*   pos_t = rp_t + N_T + 1;
  int*   csr_t = pos_t + N_T;
  int*   cnt_q = csr_t + E_T;
  int*   rp_q  = cnt_q + N_Q;
  int*   pos_q = rp_q + N_Q + 1;
  int*   csr_q = pos_q + N_Q;

  zero_i32_k<<<(N_T+255)/256,256,0,stream>>>(cnt_t, N_T);
  zero_i32_k<<<(N_Q+255)/256,256,0,stream>>>(cnt_q, N_Q);
  zero_f32_k<<<(N_Q+255)/256,256,0,stream>>>(rowsum, N_Q);
  zero_i32_k<<<1,256,0,stream>>>(flag, 1);
  detect_mask_k<<<1,256,0,stream>>>((const unsigned*)mask, flag);

  count_k<<<E_T/256,256,0,stream>>>(te+E_T, E_T, cnt_t);
  scan_k<<<1,1024,0,stream>>>(cnt_t, N_T, rp_t, pos_t);
  fill_k<<<E_T/256,256,0,stream>>>(te, te+E_T, E_T, pos_t, csr_t);
  count_k<<<E_Q/256,256,0,stream>>>(qe+E_Q, E_Q, cnt_q);
  scan_k<<<1,1024,0,stream>>>(cnt_q, N_Q, rp_q, pos_q);
  fill_k<<<E_Q/256,256,0,stream>>>(qe, qe+E_Q, E_Q, pos_q, csr_q);

  embed_k<<<N_T*32/256,256,0,stream>>>(tx, emb, xt0, N_T);
  embed_k<<<N_Q*32/256,256,0,stream>>>(qx, emb, xq0, N_Q);

  float* ct = xt0; float* nt = xt1;
  float* cq = xq0; float* nq = xq1;
  for(int l=0;l<NL;l++){
    int last = (l == NL-1);
    agg_k<<<N_T/4,256,0,stream>>>(ct, rp_t, csr_t, aggt, N_T);
    layer_k<<<N_T/128,256,0,stream>>>(aggt, ct, Wl+(size_t)l*H*H, Wr+(size_t)l*H*H,
                                      bl+(size_t)l*H, nt, etHi, etLo, N_T, last);
    agg_k<<<N_Q/4,256,0,stream>>>(cq, rp_q, csr_q, aggq, N_Q);
    layer_k<<<N_Q/128,256,0,stream>>>(aggq, cq, Wl+(size_t)l*H*H, Wr+(size_t)l*H*H,
                                      bl+(size_t)l*H, nq, eqHi, eqLo, N_Q, last);
    float* tmp;
    tmp = ct; ct = nt; nt = tmp;
    tmp = cq; cq = nq; nq = tmp;
  }

  att1_k<<<dim3(N_T/128, N_Q/128),256,0,stream>>>(eqHi, eqLo, etHi, etLo,
                                                  mask, flag, out, rowsum);
  att2_k<<<8192,256,0,stream>>>(out, rowsum);
}